// Round 6
// baseline (1270.157 us; speedup 1.0000x reference)
//
#include <hip/hip_runtime.h>
#include <hip/hip_bf16.h>

typedef __bf16 bf16_t;
typedef __bf16 bf16x8 __attribute__((ext_vector_type(8)));
typedef float  f32x4  __attribute__((ext_vector_type(4)));
typedef int    i32x4  __attribute__((ext_vector_type(4)));

static constexpr int M_ = 8192;   // 4 * 2048
static constexpr int N_ = 4096;   // out_f
static constexpr int K_ = 4096;   // in_f

// 256x256 tile, BK=64, 8 waves (2M x 4N), 512 threads.
static constexpr int BM = 256, BN = 256, BK = 64;
static constexpr int NT = K_ / BK;             // 64 K-tiles
static constexpr int HT_ELEMS  = 128 * 64;     // elems per half-tile
static constexpr int BUF_ELEMS = 2 * HT_ELEMS; // elems per K-tile buffer

#define MFMA16(a, b, c) __builtin_amdgcn_mfma_f32_16x16x32_bf16((a), (b), (c), 0, 0, 0)

// Fully fused: x fp32 -> bf16 (A) and qweight int32 * scale -> bf16 (B) are
// converted in-register during staging; no prep passes, no workspace.
// Reg-staging reproduces EXACTLY the same swizzled LDS layout as before,
// so the ds_read + MFMA 8-phase schedule is byte-identical to round 2/5.
// Staging pipeline (T14 split, 2.5-phase latency, regs as buffer):
//   P1: issue A-glob loads[T+1] (8x dwordx4)         | ds_read A0+B0, MFMA
//   P2: issue scale(4) + B-glob loads[T+1] (8x)      | ds_read B1,    MFMA
//   P3: MFMA, then vmcnt(12) -> cvt A -> ds_write A  | ds_read A1
//   P4: MFMA, then vmcnt(0)  -> cvt B -> ds_write B, lgkm(0)
__global__ __launch_bounds__(512, 2) void gemm_kernel(const float* __restrict__ X,
                                                      const int* __restrict__ Q,
                                                      const float* __restrict__ S,
                                                      const float* __restrict__ bias,
                                                      float* __restrict__ C) {
  __shared__ __align__(16) bf16_t As[2 * BUF_ELEMS];  // 64 KiB
  __shared__ __align__(16) bf16_t Bs[2 * BUF_ELEMS];  // 64 KiB

  const int tid  = threadIdx.x;
  const int lane = tid & 63;
  const int wave = tid >> 6;
  const int ln = lane & 15;
  const int lq = lane >> 4;
  const int wm = wave >> 2;   // 0..1
  const int wn = wave & 3;    // 0..3

  // XCD swizzle: each XCD owns an 8bm x 8bn rectangle of the 32x16 grid
  // (bounds per-XCD unique fetch of the fp32/int32 sources).
  const int bid   = blockIdx.x;
  const int xcd   = bid & 7;
  const int local = bid >> 3;
  const int bm = (((xcd >> 1) << 3) + (local >> 3)) * BM;
  const int bn = (((xcd & 1) << 3) + (local & 7)) * BN;

  // staging: thread t covers row (t>>3) of a 64-row chunk, 8 elems at
  // inverse-swizzled col; chunk hc = (half h = hc>>1, sub c = hc&1).
  const int r_sub = tid >> 3;
  const int g_col = ((tid & 7) ^ (r_sub & 7)) * 8;
  const int lds_off = tid * 8;

  const float* Xb[4];
  const int*   Qb[4];
  const float* Sb[4];
#pragma unroll
  for (int hc = 0; hc < 4; ++hc) {
    const int roff = (hc >> 1) * 128 + (hc & 1) * 64 + r_sub;
    Xb[hc] = X + (size_t)(bm + roff) * K_ + g_col;
    Qb[hc] = Q + (size_t)(bn + roff) * K_ + g_col;
    Sb[hc] = S + (size_t)(bn + roff) * 32;
  }

  f32x4 aL[4][2];
  i32x4 bL[4][2];
  float sc4[4];

#define ISSUE_A(T1)                                                            \
  _Pragma("unroll")                                                            \
  for (int hc = 0; hc < 4; ++hc) {                                             \
    const float* p = Xb[hc] + (size_t)(T1) * BK;                               \
    aL[hc][0] = *(const f32x4*)(p);                                            \
    aL[hc][1] = *(const f32x4*)(p + 4);                                        \
  }

#define ISSUE_SB(T1)                                                           \
  _Pragma("unroll")                                                            \
  for (int hc = 0; hc < 4; ++hc) sc4[hc] = Sb[hc][(T1) >> 1];                  \
  _Pragma("unroll")                                                            \
  for (int hc = 0; hc < 4; ++hc) {                                             \
    const int* p = Qb[hc] + (size_t)(T1) * BK;                                 \
    bL[hc][0] = *(const i32x4*)(p);                                            \
    bL[hc][1] = *(const i32x4*)(p + 4);                                        \
  }

#define CVT_WRITE_A(T1)                                                        \
  _Pragma("unroll")                                                            \
  for (int hc = 0; hc < 4; ++hc) {                                             \
    bf16x8 w;                                                                  \
    _Pragma("unroll")                                                          \
    for (int v = 0; v < 4; ++v) {                                              \
      w[v]     = (bf16_t)aL[hc][0][v];                                         \
      w[v + 4] = (bf16_t)aL[hc][1][v];                                         \
    }                                                                          \
    *(bf16x8*)(As + ((T1) & 1) * BUF_ELEMS + (hc >> 1) * HT_ELEMS +            \
               (hc & 1) * 4096 + lds_off) = w;                                 \
  }

#define CVT_WRITE_B(T1)                                                        \
  _Pragma("unroll")                                                            \
  for (int hc = 0; hc < 4; ++hc) {                                             \
    const float sc = sc4[hc];                                                  \
    bf16x8 w;                                                                  \
    _Pragma("unroll")                                                          \
    for (int v = 0; v < 4; ++v) {                                              \
      w[v]     = (bf16_t)((float)bL[hc][0][v] * sc);                           \
      w[v + 4] = (bf16_t)((float)bL[hc][1][v] * sc);                           \
    }                                                                          \
    *(bf16x8*)(Bs + ((T1) & 1) * BUF_ELEMS + (hc >> 1) * HT_ELEMS +            \
               (hc & 1) * 4096 + lds_off) = w;                                 \
  }

  // ds_read addressing (T2 swizzle on the k-column within each 64-elem row)
  const int kx0 = (lq * 8) ^ ((ln & 7) * 8);
  const int kx1 = (32 + lq * 8) ^ ((ln & 7) * 8);
  const int a_row_off = (wm * 16 + ln) * 64;
  const int b_row_off = (wn * 32 + ln) * 64;

  f32x4 acc[8][4] = {};

  // ---- prologue: stage tile 0 through regs ----
  ISSUE_A(0)
  ISSUE_SB(0)
  asm volatile("s_waitcnt vmcnt(12)" ::: "memory");  // A arrived (S+B still out)
  CVT_WRITE_A(0)
  asm volatile("s_waitcnt vmcnt(0)" ::: "memory");   // S+B arrived
  CVT_WRITE_B(0)
  asm volatile("s_waitcnt lgkmcnt(0)" ::: "memory");
  __builtin_amdgcn_s_barrier();

  for (int T = 0; T < NT; ++T) {
    const bf16_t* as = As + (T & 1) * BUF_ELEMS;
    const bf16_t* bs = Bs + (T & 1) * BUF_ELEMS;
    bf16x8 af[4][2], bqA[2][2], bqB[2][2];
    const bool stage = (T + 1 < NT);

    // ---- phase 1: ds_read A0 (8) + B0 (4); issue A[T+1]; mfma i0-3 x j0-1
#pragma unroll
    for (int i = 0; i < 4; ++i) {
      const bf16_t* p = as + a_row_off + i * 2048;
      af[i][0] = *(const bf16x8*)(p + kx0);
      af[i][1] = *(const bf16x8*)(p + kx1);
    }
#pragma unroll
    for (int j = 0; j < 2; ++j) {
      const bf16_t* p = bs + b_row_off + j * 1024;
      bqA[j][0] = *(const bf16x8*)(p + kx0);
      bqA[j][1] = *(const bf16x8*)(p + kx1);
    }
    if (stage) { ISSUE_A(T + 1) }
    asm volatile("s_waitcnt lgkmcnt(8)" ::: "memory");
    __builtin_amdgcn_s_barrier();
    asm volatile("s_waitcnt lgkmcnt(0)" ::: "memory");
    __builtin_amdgcn_sched_barrier(0);
    __builtin_amdgcn_s_setprio(1);
#pragma unroll
    for (int i = 0; i < 4; ++i)
#pragma unroll
      for (int j = 0; j < 2; ++j) {
        acc[i][j] = MFMA16(af[i][0], bqA[j][0], acc[i][j]);
        acc[i][j] = MFMA16(af[i][1], bqA[j][1], acc[i][j]);
      }
    __builtin_amdgcn_s_setprio(0);
    __builtin_amdgcn_s_barrier();

    // ---- phase 2: ds_read B1 (4); issue scales+B[T+1]; mfma i0-3 x j2-3
#pragma unroll
    for (int j = 0; j < 2; ++j) {
      const bf16_t* p = bs + HT_ELEMS + b_row_off + j * 1024;
      bqB[j][0] = *(const bf16x8*)(p + kx0);
      bqB[j][1] = *(const bf16x8*)(p + kx1);
    }
    if (stage) { ISSUE_SB(T + 1) }
    __builtin_amdgcn_s_barrier();
    asm volatile("s_waitcnt lgkmcnt(0)" ::: "memory");
    __builtin_amdgcn_sched_barrier(0);
    __builtin_amdgcn_s_setprio(1);
#pragma unroll
    for (int i = 0; i < 4; ++i)
#pragma unroll
      for (int j = 0; j < 2; ++j) {
        acc[i][j + 2] = MFMA16(af[i][0], bqB[j][0], acc[i][j + 2]);
        acc[i][j + 2] = MFMA16(af[i][1], bqB[j][1], acc[i][j + 2]);
      }
    __builtin_amdgcn_s_setprio(0);
    __builtin_amdgcn_s_barrier();

    // ---- phase 3: ds_read A1 (8, reuse af); mfma i4-7 x j2-3;
    //      then retire A[T+1] loads -> cvt -> ds_write (hides under MFMA tail)
#pragma unroll
    for (int i = 0; i < 4; ++i) {
      const bf16_t* p = as + HT_ELEMS + a_row_off + i * 2048;
      af[i][0] = *(const bf16x8*)(p + kx0);
      af[i][1] = *(const bf16x8*)(p + kx1);
    }
    __builtin_amdgcn_s_barrier();
    asm volatile("s_waitcnt lgkmcnt(0)" ::: "memory");
    __builtin_amdgcn_sched_barrier(0);
    __builtin_amdgcn_s_setprio(1);
#pragma unroll
    for (int i = 0; i < 4; ++i)
#pragma unroll
      for (int j = 0; j < 2; ++j) {
        acc[i + 4][j + 2] = MFMA16(af[i][0], bqB[j][0], acc[i + 4][j + 2]);
        acc[i + 4][j + 2] = MFMA16(af[i][1], bqB[j][1], acc[i + 4][j + 2]);
      }
    __builtin_amdgcn_s_setprio(0);
    if (stage) {
      asm volatile("s_waitcnt vmcnt(12)" ::: "memory");  // A[T+1] arrived
      CVT_WRITE_A(T + 1)
    }
    __builtin_amdgcn_s_barrier();

    // ---- phase 4: mfma i4-7 x j0-1; then retire S+B[T+1] -> cvt -> ds_write
    __builtin_amdgcn_s_setprio(1);
#pragma unroll
    for (int i = 0; i < 4; ++i)
#pragma unroll
      for (int j = 0; j < 2; ++j) {
        acc[i + 4][j] = MFMA16(af[i][0], bqA[j][0], acc[i + 4][j]);
        acc[i + 4][j] = MFMA16(af[i][1], bqA[j][1], acc[i + 4][j]);
      }
    __builtin_amdgcn_s_setprio(0);
    if (stage) {
      asm volatile("s_waitcnt vmcnt(0)" ::: "memory");   // S+B[T+1] arrived
      CVT_WRITE_B(T + 1)
    }
    asm volatile("s_waitcnt lgkmcnt(0)" ::: "memory");   // writes visible pre-barrier
    __builtin_amdgcn_s_barrier();
  }

  // epilogue: C/D layout col=lane&15, row=(lane>>4)*4+reg  [m89/m91 verified]
  // nt stores: C is write-once.
#pragma unroll
  for (int j = 0; j < 4; ++j) {
    const int col = bn + (j >> 1) * 128 + wn * 32 + (j & 1) * 16 + ln;
    const float bv = bias[col];
#pragma unroll
    for (int i = 0; i < 8; ++i) {
      const int row0 = bm + (i >> 2) * 128 + (i & 3) * 32 + wm * 16 + lq * 4;
      float* cp = C + (size_t)row0 * N_ + col;
#pragma unroll
      for (int r = 0; r < 4; ++r) {
        __builtin_nontemporal_store(acc[i][j][r] + bv, cp);
        cp += N_;
      }
    }
  }
#undef ISSUE_A
#undef ISSUE_SB
#undef CVT_WRITE_A
#undef CVT_WRITE_B
}

extern "C" void kernel_launch(void* const* d_in, const int* in_sizes, int n_in,
                              void* d_out, int out_size, void* d_ws, size_t ws_size,
                              hipStream_t stream) {
  const float* x    = (const float*)d_in[0];  // [4,2048,4096] fp32
  const int*   qw   = (const int*)d_in[1];    // [4096,4096] int32 in [0,16)
  const float* sc   = (const float*)d_in[2];  // [4096,32] fp32
  const float* bias = (const float*)d_in[3];  // [4096] fp32
  float* out = (float*)d_out;                 // [8192,4096] fp32

  const int nwg = (N_ / BN) * (M_ / BM);  // 16 * 32 = 512
  gemm_kernel<<<nwg, 512, 0, stream>>>(x, qw, sc, bias, out);
}

// Round 7
// 489.850 us; speedup vs baseline: 2.5929x; 2.5929x over previous
//
#include <hip/hip_runtime.h>
#include <hip/hip_bf16.h>

typedef __bf16 bf16_t;
typedef __bf16 bf16x8 __attribute__((ext_vector_type(8)));
typedef float  f32x4  __attribute__((ext_vector_type(4)));
typedef int    i32x4  __attribute__((ext_vector_type(4)));

static constexpr int M_ = 8192;   // 4 * 2048
static constexpr int N_ = 4096;   // out_f
static constexpr int K_ = 4096;   // in_f

// GEMM geometry: 256x256 tile, BK=64, 8 waves (2M x 4N), 512 threads.
static constexpr int BM = 256, BN = 256, BK = 64;
static constexpr int NT = K_ / BK;             // 64 K-tiles
static constexpr int HT_ELEMS  = 128 * 64;     // elems per half-tile
static constexpr int BUF_ELEMS = 2 * HT_ELEMS; // elems per K-tile buffer

// async global->LDS, 16B per lane. LDS dest must be wave-uniform base + lane*16.
__device__ __forceinline__ void load_lds16(const bf16_t* g, bf16_t* l) {
  __builtin_amdgcn_global_load_lds(
      (const __attribute__((address_space(1))) void*)g,
      (__attribute__((address_space(3))) void*)l,
      16, 0, 0);
}

#define MFMA16(a, b, c) __builtin_amdgcn_mfma_f32_16x16x32_bf16((a), (b), (c), 0, 0, 0)

// ---- pass 1: x fp32 -> bf16 (nt loads: read-once) -------------------------
__global__ __launch_bounds__(256) void cvt_x_kernel(const float* __restrict__ x,
                                                    bf16_t* __restrict__ xb) {
  const size_t i = ((size_t)blockIdx.x * 256 + threadIdx.x) * 8;
  const f32x4 f0 = __builtin_nontemporal_load((const f32x4*)(x + i));
  const f32x4 f1 = __builtin_nontemporal_load((const f32x4*)(x + i + 4));
  bf16x8 o;
  o[0] = (bf16_t)f0[0]; o[1] = (bf16_t)f0[1]; o[2] = (bf16_t)f0[2]; o[3] = (bf16_t)f0[3];
  o[4] = (bf16_t)f1[0]; o[5] = (bf16_t)f1[1]; o[6] = (bf16_t)f1[2]; o[7] = (bf16_t)f1[3];
  *(bf16x8*)(xb + i) = o;   // cached store: gemm re-reads this soon
}

// ---- pass 2: W[o][i] = q[o][i] * scales[o][i/128] -> bf16 ----------------
__global__ __launch_bounds__(256) void dequant_kernel(const int* __restrict__ q,
                                                      const float* __restrict__ s,
                                                      bf16_t* __restrict__ wb) {
  const size_t base = ((size_t)blockIdx.x * 256 + threadIdx.x) * 8;
  const int o  = (int)(base >> 12);
  const int ii = (int)(base & 4095);
  const float sc = s[(o << 5) + (ii >> 7)];
  const i32x4 q0 = __builtin_nontemporal_load((const i32x4*)(q + base));
  const i32x4 q1 = __builtin_nontemporal_load((const i32x4*)(q + base + 4));
  bf16x8 w;
  w[0] = (bf16_t)((float)q0[0] * sc); w[1] = (bf16_t)((float)q0[1] * sc);
  w[2] = (bf16_t)((float)q0[2] * sc); w[3] = (bf16_t)((float)q0[3] * sc);
  w[4] = (bf16_t)((float)q1[0] * sc); w[5] = (bf16_t)((float)q1[1] * sc);
  w[6] = (bf16_t)((float)q1[2] * sc); w[7] = (bf16_t)((float)q1[3] * sc);
  *(bf16x8*)(wb + base) = w;  // cached store: gemm re-reads this soon
}

// ---- pass 3: C = A . B^T + bias, 8-phase with balanced ds_reads ----------
// Round-5 structure + carried-B0: phase 4 of tile T reads tile T+1's B-half0
// (provably resident after P4's vmcnt(6)+barrier), so the per-phase ds_read
// distribution is 8/4/8/4 instead of 12/4/8/0. T-loop unrolled x2 for static
// bq0/bq1 register indexing (rule #20). Everything else identical to round 5.
__global__ __launch_bounds__(512, 2) void gemm_kernel(const bf16_t* __restrict__ A,
                                                      const bf16_t* __restrict__ B,
                                                      const float* __restrict__ bias,
                                                      float* __restrict__ C) {
  __shared__ __align__(16) bf16_t As[2 * BUF_ELEMS];  // 64 KiB
  __shared__ __align__(16) bf16_t Bs[2 * BUF_ELEMS];  // 64 KiB

  const int tid  = threadIdx.x;
  const int lane = tid & 63;
  const int wave = tid >> 6;
  const int ln = lane & 15;
  const int lq = lane >> 4;
  const int wm = wave >> 2;   // 0..1
  const int wn = wave & 3;    // 0..3

  // T1: XCD-bijective swizzle (512 wgs = 8 XCD x 64).
  const int bid = blockIdx.x;
  const int wg  = (bid & 7) * 64 + (bid >> 3);
  const int bn  = (wg & 15) * BN;
  const int bm  = (wg >> 4) * BM;

  // staging: thread t covers row (t>>3) of a 64-row chunk, 16B at inverse-swizzled col.
  const int r_sub = tid >> 3;
  const int g_col = ((tid & 7) ^ (r_sub & 7)) * 8;
  const size_t a_base = (size_t)(bm + r_sub) * K_ + g_col;
  const size_t b_base = (size_t)(bn + r_sub) * K_ + g_col;
  const int lds_off = tid * 8;

  auto stageA = [&](int t, int h) {
    bf16_t* d = As + (t & 1) * BUF_ELEMS + h * HT_ELEMS + lds_off;
    const bf16_t* s = A + a_base + (size_t)(h * 128) * K_ + (size_t)t * BK;
    load_lds16(s, d);
    load_lds16(s + (size_t)64 * K_, d + 4096);
  };
  auto stageB = [&](int t, int h) {
    bf16_t* d = Bs + (t & 1) * BUF_ELEMS + h * HT_ELEMS + lds_off;
    const bf16_t* s = B + b_base + (size_t)(h * 128) * K_ + (size_t)t * BK;
    load_lds16(s, d);
    load_lds16(s + (size_t)64 * K_, d + 4096);
  };

  // ds_read addressing (T2 swizzle on the k-column within each 64-elem row)
  const int kx0 = (lq * 8) ^ ((ln & 7) * 8);
  const int kx1 = (32 + lq * 8) ^ ((ln & 7) * 8);
  const int a_row_off = (wm * 16 + ln) * 64;
  const int b_row_off = (wn * 32 + ln) * 64;

  f32x4 acc[8][4] = {};
  bf16x8 bq0[2][2], bq1[2][2];   // B-half0 ping-pong across tiles

// One K-tile, 4 phases x 16 MFMA. BQC_ = this tile's B-half0 (pre-read in
// the previous tile's P4), BQN_ = next tile's B-half0 (read in P4 here from
// NBS_ = the other buffer).
#define TILE_BODY(T_, AS_, BS_, NBS_, BQC_, BQN_)                              \
  {                                                                            \
    const bf16_t* as = (AS_);                                                  \
    const bf16_t* bs = (BS_);                                                  \
    bf16x8 af[4][2], bqB[2][2];                                                \
    /* P1: read A-half0 (8); stage A1[T+1]; mfma i0-3 x j0-1 */                \
    _Pragma("unroll")                                                          \
    for (int i = 0; i < 4; ++i) {                                              \
      const bf16_t* p = as + a_row_off + i * 2048;                             \
      af[i][0] = *(const bf16x8*)(p + kx0);                                    \
      af[i][1] = *(const bf16x8*)(p + kx1);                                    \
    }                                                                          \
    if ((T_) + 1 < NT) stageA((T_) + 1, 1);                                    \
    asm volatile("s_waitcnt lgkmcnt(4)" ::: "memory");                         \
    __builtin_amdgcn_s_barrier();                                              \
    asm volatile("s_waitcnt lgkmcnt(0)" ::: "memory");                         \
    __builtin_amdgcn_sched_barrier(0);                                         \
    __builtin_amdgcn_s_setprio(1);                                             \
    _Pragma("unroll")                                                          \
    for (int i = 0; i < 4; ++i)                                                \
      _Pragma("unroll")                                                        \
      for (int j = 0; j < 2; ++j) {                                            \
        acc[i][j] = MFMA16(af[i][0], BQC_[j][0], acc[i][j]);                   \
        acc[i][j] = MFMA16(af[i][1], BQC_[j][1], acc[i][j]);                   \
      }                                                                        \
    __builtin_amdgcn_s_setprio(0);                                             \
    __builtin_amdgcn_s_barrier();                                              \
    /* P2: read B-half1 (4); stage A0[T+2]; mfma i0-3 x j2-3 */                \
    _Pragma("unroll")                                                          \
    for (int j = 0; j < 2; ++j) {                                              \
      const bf16_t* p = bs + HT_ELEMS + b_row_off + j * 1024;                  \
      bqB[j][0] = *(const bf16x8*)(p + kx0);                                   \
      bqB[j][1] = *(const bf16x8*)(p + kx1);                                   \
    }                                                                          \
    if ((T_) + 2 < NT) stageA((T_) + 2, 0);                                    \
    __builtin_amdgcn_s_barrier();                                              \
    asm volatile("s_waitcnt lgkmcnt(0)" ::: "memory");                         \
    __builtin_amdgcn_sched_barrier(0);                                         \
    __builtin_amdgcn_s_setprio(1);                                             \
    _Pragma("unroll")                                                          \
    for (int i = 0; i < 4; ++i)                                                \
      _Pragma("unroll")                                                        \
      for (int j = 0; j < 2; ++j) {                                            \
        acc[i][j + 2] = MFMA16(af[i][0], bqB[j][0], acc[i][j + 2]);            \
        acc[i][j + 2] = MFMA16(af[i][1], bqB[j][1], acc[i][j + 2]);            \
      }                                                                        \
    __builtin_amdgcn_s_setprio(0);                                             \
    __builtin_amdgcn_s_barrier();                                              \
    /* P3: read A-half1 (8, reuse af); stage B0[T+2]; mfma i4-7 x j2-3 */      \
    _Pragma("unroll")                                                          \
    for (int i = 0; i < 4; ++i) {                                              \
      const bf16_t* p = as + HT_ELEMS + a_row_off + i * 2048;                  \
      af[i][0] = *(const bf16x8*)(p + kx0);                                    \
      af[i][1] = *(const bf16x8*)(p + kx1);                                    \
    }                                                                          \
    if ((T_) + 2 < NT) stageB((T_) + 2, 0);                                    \
    __builtin_amdgcn_s_barrier();                                              \
    asm volatile("s_waitcnt lgkmcnt(0)" ::: "memory");                         \
    __builtin_amdgcn_sched_barrier(0);                                         \
    __builtin_amdgcn_s_setprio(1);                                             \
    _Pragma("unroll")                                                          \
    for (int i = 0; i < 4; ++i)                                                \
      _Pragma("unroll")                                                        \
      for (int j = 0; j < 2; ++j) {                                            \
        acc[i + 4][j + 2] = MFMA16(af[i][0], bqB[j][0], acc[i + 4][j + 2]);    \
        acc[i + 4][j + 2] = MFMA16(af[i][1], bqB[j][1], acc[i + 4][j + 2]);    \
      }                                                                        \
    __builtin_amdgcn_s_setprio(0);                                             \
    __builtin_amdgcn_s_barrier();                                              \
    /* P4: stage B1[T+2]; counted vmcnt; read next-tile B0 (4) under MFMA;     \
       mfma i4-7 x j0-1 */                                                     \
    if ((T_) + 2 < NT) {                                                       \
      stageB((T_) + 2, 1);                                                     \
      asm volatile("s_waitcnt vmcnt(6)" ::: "memory");                         \
    } else {                                                                   \
      asm volatile("s_waitcnt vmcnt(0)" ::: "memory");                         \
    }                                                                          \
    __builtin_amdgcn_s_barrier();                                              \
    if ((T_) + 1 < NT) {                                                       \
      const bf16_t* nbs = (NBS_);                                              \
      _Pragma("unroll")                                                        \
      for (int j = 0; j < 2; ++j) {                                            \
        const bf16_t* p = nbs + b_row_off + j * 1024;                          \
        BQN_[j][0] = *(const bf16x8*)(p + kx0);                                \
        BQN_[j][1] = *(const bf16x8*)(p + kx1);                                \
      }                                                                        \
    }                                                                          \
    __builtin_amdgcn_sched_barrier(0);                                         \
    __builtin_amdgcn_s_setprio(1);                                             \
    _Pragma("unroll")                                                          \
    for (int i = 0; i < 4; ++i)                                                \
      _Pragma("unroll")                                                        \
      for (int j = 0; j < 2; ++j) {                                            \
        acc[i + 4][j] = MFMA16(af[i][0], BQC_[j][0], acc[i + 4][j]);           \
        acc[i + 4][j] = MFMA16(af[i][1], BQC_[j][1], acc[i + 4][j]);           \
      }                                                                        \
    __builtin_amdgcn_s_setprio(0);                                             \
    __builtin_amdgcn_s_barrier();                                              \
  }

  // prologue: tile0 {A0,B0,B1,A1} + tile1 {A0,B0,B1}; retire tile0 (8 loads),
  // 3 half-tiles (6 loads) stay in flight; then pre-read B0[0].
  stageA(0, 0); stageB(0, 0); stageB(0, 1); stageA(0, 1);
  stageA(1, 0); stageB(1, 0); stageB(1, 1);
  asm volatile("s_waitcnt vmcnt(6)" ::: "memory");
  __builtin_amdgcn_s_barrier();
#pragma unroll
  for (int j = 0; j < 2; ++j) {
    const bf16_t* p = Bs + b_row_off + j * 1024;
    bq0[j][0] = *(const bf16x8*)(p + kx0);
    bq0[j][1] = *(const bf16x8*)(p + kx1);
  }

  for (int T = 0; T < NT; T += 2) {
    TILE_BODY(T,     As,             Bs,             Bs + BUF_ELEMS, bq0, bq1)
    TILE_BODY(T + 1, As + BUF_ELEMS, Bs + BUF_ELEMS, Bs,             bq1, bq0)
  }
#undef TILE_BODY

  // epilogue: C/D layout col=lane&15, row=(lane>>4)*4+reg  [m89/m91 verified]
  // nt stores: C is write-once.
#pragma unroll
  for (int j = 0; j < 4; ++j) {
    const int col = bn + (j >> 1) * 128 + wn * 32 + (j & 1) * 16 + ln;
    const float bv = bias[col];
#pragma unroll
    for (int i = 0; i < 8; ++i) {
      const int row0 = bm + (i >> 2) * 128 + (i & 3) * 32 + wm * 16 + lq * 4;
      float* cp = C + (size_t)row0 * N_ + col;
#pragma unroll
      for (int r = 0; r < 4; ++r) {
        __builtin_nontemporal_store(acc[i][j][r] + bv, cp);
        cp += N_;
      }
    }
  }
}

extern "C" void kernel_launch(void* const* d_in, const int* in_sizes, int n_in,
                              void* d_out, int out_size, void* d_ws, size_t ws_size,
                              hipStream_t stream) {
  const float* x    = (const float*)d_in[0];  // [4,2048,4096] fp32
  const int*   qw   = (const int*)d_in[1];    // [4096,4096] int32 in [0,16)
  const float* sc   = (const float*)d_in[2];  // [4096,32] fp32
  const float* bias = (const float*)d_in[3];  // [4096] fp32
  float* out = (float*)d_out;                 // [8192,4096] fp32

  bf16_t* xb = (bf16_t*)d_ws;                 // M_*K_ bf16 = 64 MiB
  bf16_t* wb = xb + (size_t)M_ * K_;          // N_*K_ bf16 = 32 MiB

  cvt_x_kernel<<<(int)(((size_t)M_ * K_) / (256 * 8)), 256, 0, stream>>>(x, xb);
  dequant_kernel<<<(int)(((size_t)N_ * K_) / (256 * 8)), 256, 0, stream>>>(qw, sc, wb);

  const int nwg = (N_ / BN) * (M_ / BM);  // 16 * 32 = 512
  gemm_kernel<<<nwg, 512, 0, stream>>>(xb, wb, bias, out);
}

// Round 8
// 479.683 us; speedup vs baseline: 2.6479x; 1.0212x over previous
//
#include <hip/hip_runtime.h>
#include <hip/hip_bf16.h>

typedef __bf16 bf16_t;
typedef __bf16 bf16x8 __attribute__((ext_vector_type(8)));
typedef float  f32x4  __attribute__((ext_vector_type(4)));
typedef int    i32x4  __attribute__((ext_vector_type(4)));

static constexpr int M_ = 8192;   // 4 * 2048
static constexpr int N_ = 4096;   // out_f
static constexpr int K_ = 4096;   // in_f

// GEMM geometry: 256x256 tile, BK=64, 8 waves (2M x 4N), 512 threads.
static constexpr int BM = 256, BN = 256, BK = 64;
static constexpr int NT = K_ / BK;             // 64 K-tiles
static constexpr int HT_ELEMS  = 128 * 64;     // elems per half-tile
static constexpr int BUF_ELEMS = 2 * HT_ELEMS; // elems per K-tile buffer

// async global->LDS, 16B per lane. LDS dest must be wave-uniform base + lane*16.
__device__ __forceinline__ void load_lds16(const bf16_t* g, bf16_t* l) {
  __builtin_amdgcn_global_load_lds(
      (const __attribute__((address_space(1))) void*)g,
      (__attribute__((address_space(3))) void*)l,
      16, 0, 0);
}

#define MFMA16(a, b, c) __builtin_amdgcn_mfma_f32_16x16x32_bf16((a), (b), (c), 0, 0, 0)

// ---- pass 1: x fp32 -> bf16 (nt loads: read-once) -------------------------
__global__ __launch_bounds__(256) void cvt_x_kernel(const float* __restrict__ x,
                                                    bf16_t* __restrict__ xb) {
  const size_t i = ((size_t)blockIdx.x * 256 + threadIdx.x) * 8;
  const f32x4 f0 = __builtin_nontemporal_load((const f32x4*)(x + i));
  const f32x4 f1 = __builtin_nontemporal_load((const f32x4*)(x + i + 4));
  bf16x8 o;
  o[0] = (bf16_t)f0[0]; o[1] = (bf16_t)f0[1]; o[2] = (bf16_t)f0[2]; o[3] = (bf16_t)f0[3];
  o[4] = (bf16_t)f1[0]; o[5] = (bf16_t)f1[1]; o[6] = (bf16_t)f1[2]; o[7] = (bf16_t)f1[3];
  *(bf16x8*)(xb + i) = o;   // cached store: gemm re-reads this soon
}

// ---- pass 2: W[o][i] = q[o][i] * scales[o][i/128] -> bf16 ----------------
__global__ __launch_bounds__(256) void dequant_kernel(const int* __restrict__ q,
                                                      const float* __restrict__ s,
                                                      bf16_t* __restrict__ wb) {
  const size_t base = ((size_t)blockIdx.x * 256 + threadIdx.x) * 8;
  const int o  = (int)(base >> 12);
  const int ii = (int)(base & 4095);
  const float sc = s[(o << 5) + (ii >> 7)];
  const i32x4 q0 = __builtin_nontemporal_load((const i32x4*)(q + base));
  const i32x4 q1 = __builtin_nontemporal_load((const i32x4*)(q + base + 4));
  bf16x8 w;
  w[0] = (bf16_t)((float)q0[0] * sc); w[1] = (bf16_t)((float)q0[1] * sc);
  w[2] = (bf16_t)((float)q0[2] * sc); w[3] = (bf16_t)((float)q0[3] * sc);
  w[4] = (bf16_t)((float)q1[0] * sc); w[5] = (bf16_t)((float)q1[1] * sc);
  w[6] = (bf16_t)((float)q1[2] * sc); w[7] = (bf16_t)((float)q1[3] * sc);
  *(bf16x8*)(wb + base) = w;  // cached store: gemm re-reads this soon
}

// ---- pass 3: C = A . B^T + bias, 8-phase, fine-grained lgkm waits ---------
// Round-5 structure with ONE change: no forced lgkmcnt(0)+sched_barrier(0)
// BEFORE the MFMA cluster. The phase's ds_reads are plain C++ loads, so the
// compiler emits per-dependency lgkmcnt(N) and the first MFMA starts as soon
// as ITS operands land, overlapping the tail reads. Correctness only needs
// "my reads done before the CLOSING barrier" -> lgkmcnt(0) moved after MFMA.
// Fragment interleave:
//   A frag i (0..7): row = (i>>2)*128 + (i&3)*32 + wm*16
//   B frag j (0..3): row = (j>>1)*128 + wn*32 + (j&1)*16
__global__ __launch_bounds__(512, 2) void gemm_kernel(const bf16_t* __restrict__ A,
                                                      const bf16_t* __restrict__ B,
                                                      const float* __restrict__ bias,
                                                      float* __restrict__ C) {
  __shared__ __align__(16) bf16_t As[2 * BUF_ELEMS];  // 64 KiB
  __shared__ __align__(16) bf16_t Bs[2 * BUF_ELEMS];  // 64 KiB

  const int tid  = threadIdx.x;
  const int lane = tid & 63;
  const int wave = tid >> 6;
  const int ln = lane & 15;
  const int lq = lane >> 4;
  const int wm = wave >> 2;   // 0..1
  const int wn = wave & 3;    // 0..3

  // T1: XCD-bijective swizzle (512 wgs = 8 XCD x 64).
  const int bid = blockIdx.x;
  const int wg  = (bid & 7) * 64 + (bid >> 3);
  const int bn  = (wg & 15) * BN;
  const int bm  = (wg >> 4) * BM;

  // staging: thread t covers row (t>>3) of a 64-row chunk, 16B at inverse-swizzled col.
  const int r_sub = tid >> 3;
  const int g_col = ((tid & 7) ^ (r_sub & 7)) * 8;
  const size_t a_base = (size_t)(bm + r_sub) * K_ + g_col;
  const size_t b_base = (size_t)(bn + r_sub) * K_ + g_col;
  const int lds_off = tid * 8;

  auto stageA = [&](int t, int h) {
    bf16_t* d = As + (t & 1) * BUF_ELEMS + h * HT_ELEMS + lds_off;
    const bf16_t* s = A + a_base + (size_t)(h * 128) * K_ + (size_t)t * BK;
    load_lds16(s, d);
    load_lds16(s + (size_t)64 * K_, d + 4096);
  };
  auto stageB = [&](int t, int h) {
    bf16_t* d = Bs + (t & 1) * BUF_ELEMS + h * HT_ELEMS + lds_off;
    const bf16_t* s = B + b_base + (size_t)(h * 128) * K_ + (size_t)t * BK;
    load_lds16(s, d);
    load_lds16(s + (size_t)64 * K_, d + 4096);
  };

  // ds_read addressing (T2 swizzle on the k-column within each 64-elem row)
  const int kx0 = (lq * 8) ^ ((ln & 7) * 8);
  const int kx1 = (32 + lq * 8) ^ ((ln & 7) * 8);
  const int a_row_off = (wm * 16 + ln) * 64;
  const int b_row_off = (wn * 32 + ln) * 64;

  f32x4 acc[8][4] = {};

  // prologue: tile0 {A0,B0,B1,A1} + tile1 {A0,B0,B1}; retire tile0, 3 HT in flight.
  stageA(0, 0); stageB(0, 0); stageB(0, 1); stageA(0, 1);
  stageA(1, 0); stageB(1, 0); stageB(1, 1);
  asm volatile("s_waitcnt vmcnt(6)" ::: "memory");
  __builtin_amdgcn_s_barrier();

  for (int T = 0; T < NT; ++T) {
    const bf16_t* as = As + (T & 1) * BUF_ELEMS;
    const bf16_t* bs = Bs + (T & 1) * BUF_ELEMS;
    bf16x8 af[4][2], bqA[2][2], bqB[2][2];

    // ---- phase 1: read A-half0 (8) + B-half0 (4); stage A1[T+1]; mfma i0-3 x j0-1
#pragma unroll
    for (int i = 0; i < 4; ++i) {
      const bf16_t* p = as + a_row_off + i * 2048;
      af[i][0] = *(const bf16x8*)(p + kx0);
      af[i][1] = *(const bf16x8*)(p + kx1);
    }
#pragma unroll
    for (int j = 0; j < 2; ++j) {
      const bf16_t* p = bs + b_row_off + j * 1024;
      bqA[j][0] = *(const bf16x8*)(p + kx0);
      bqA[j][1] = *(const bf16x8*)(p + kx1);
    }
    if (T + 1 < NT) stageA(T + 1, 1);
    __builtin_amdgcn_s_barrier();
    __builtin_amdgcn_s_setprio(1);
#pragma unroll
    for (int i = 0; i < 4; ++i)
#pragma unroll
      for (int j = 0; j < 2; ++j) {
        acc[i][j] = MFMA16(af[i][0], bqA[j][0], acc[i][j]);
        acc[i][j] = MFMA16(af[i][1], bqA[j][1], acc[i][j]);
      }
    __builtin_amdgcn_s_setprio(0);
    asm volatile("s_waitcnt lgkmcnt(0)" ::: "memory");  // my reads done pre-overwrite
    __builtin_amdgcn_s_barrier();

    // ---- phase 2: read B-half1 (4); stage A0[T+2]; mfma i0-3 x j2-3
#pragma unroll
    for (int j = 0; j < 2; ++j) {
      const bf16_t* p = bs + HT_ELEMS + b_row_off + j * 1024;
      bqB[j][0] = *(const bf16x8*)(p + kx0);
      bqB[j][1] = *(const bf16x8*)(p + kx1);
    }
    if (T + 2 < NT) stageA(T + 2, 0);
    __builtin_amdgcn_s_barrier();
    __builtin_amdgcn_s_setprio(1);
#pragma unroll
    for (int i = 0; i < 4; ++i)
#pragma unroll
      for (int j = 0; j < 2; ++j) {
        acc[i][j + 2] = MFMA16(af[i][0], bqB[j][0], acc[i][j + 2]);
        acc[i][j + 2] = MFMA16(af[i][1], bqB[j][1], acc[i][j + 2]);
      }
    __builtin_amdgcn_s_setprio(0);
    asm volatile("s_waitcnt lgkmcnt(0)" ::: "memory");
    __builtin_amdgcn_s_barrier();

    // ---- phase 3: read A-half1 (8, reuse af regs); stage B0[T+2]; mfma i4-7 x j2-3
#pragma unroll
    for (int i = 0; i < 4; ++i) {
      const bf16_t* p = as + HT_ELEMS + a_row_off + i * 2048;
      af[i][0] = *(const bf16x8*)(p + kx0);
      af[i][1] = *(const bf16x8*)(p + kx1);
    }
    if (T + 2 < NT) stageB(T + 2, 0);
    __builtin_amdgcn_s_barrier();
    __builtin_amdgcn_s_setprio(1);
#pragma unroll
    for (int i = 0; i < 4; ++i)
#pragma unroll
      for (int j = 0; j < 2; ++j) {
        acc[i + 4][j + 2] = MFMA16(af[i][0], bqB[j][0], acc[i + 4][j + 2]);
        acc[i + 4][j + 2] = MFMA16(af[i][1], bqB[j][1], acc[i + 4][j + 2]);
      }
    __builtin_amdgcn_s_setprio(0);
    asm volatile("s_waitcnt lgkmcnt(0)" ::: "memory");
    __builtin_amdgcn_s_barrier();

    // ---- phase 4: no reads; stage B1[T+2]; counted vmcnt; mfma i4-7 x j0-1
    if (T + 2 < NT) {
      stageB(T + 2, 1);
      // retires through A1[T+1] (everything tile T+1 reads); keeps
      // A0/B0/B1[T+2] (3 half-tiles = 6 loads) in flight across the barrier.
      asm volatile("s_waitcnt vmcnt(6)" ::: "memory");
    } else {
      asm volatile("s_waitcnt vmcnt(0)" ::: "memory");  // epilogue drain
    }
    __builtin_amdgcn_s_barrier();
    __builtin_amdgcn_sched_barrier(0);  // P4 MFMAs have no same-phase read deps:
                                        // pin them here (rule #18 hoist guard)
    __builtin_amdgcn_s_setprio(1);
#pragma unroll
    for (int i = 0; i < 4; ++i)
#pragma unroll
      for (int j = 0; j < 2; ++j) {
        acc[i + 4][j] = MFMA16(af[i][0], bqA[j][0], acc[i + 4][j]);
        acc[i + 4][j] = MFMA16(af[i][1], bqA[j][1], acc[i + 4][j]);
      }
    __builtin_amdgcn_s_setprio(0);
    __builtin_amdgcn_s_barrier();
  }

  // epilogue: C/D layout col=lane&15, row=(lane>>4)*4+reg  [m89/m91 verified]
  // nt stores: C is write-once.
#pragma unroll
  for (int j = 0; j < 4; ++j) {
    const int col = bn + (j >> 1) * 128 + wn * 32 + (j & 1) * 16 + ln;
    const float bv = bias[col];
#pragma unroll
    for (int i = 0; i < 8; ++i) {
      const int row0 = bm + (i >> 2) * 128 + (i & 3) * 32 + wm * 16 + lq * 4;
      float* cp = C + (size_t)row0 * N_ + col;
#pragma unroll
      for (int r = 0; r < 4; ++r) {
        __builtin_nontemporal_store(acc[i][j][r] + bv, cp);
        cp += N_;
      }
    }
  }
}

extern "C" void kernel_launch(void* const* d_in, const int* in_sizes, int n_in,
                              void* d_out, int out_size, void* d_ws, size_t ws_size,
                              hipStream_t stream) {
  const float* x    = (const float*)d_in[0];  // [4,2048,4096] fp32
  const int*   qw   = (const int*)d_in[1];    // [4096,4096] int32 in [0,16)
  const float* sc   = (const float*)d_in[2];  // [4096,32] fp32
  const float* bias = (const float*)d_in[3];  // [4096] fp32
  float* out = (float*)d_out;                 // [8192,4096] fp32

  bf16_t* xb = (bf16_t*)d_ws;                 // M_*K_ bf16 = 64 MiB
  bf16_t* wb = xb + (size_t)M_ * K_;          // N_*K_ bf16 = 32 MiB

  cvt_x_kernel<<<(int)(((size_t)M_ * K_) / (256 * 8)), 256, 0, stream>>>(x, xb);
  dequant_kernel<<<(int)(((size_t)N_ * K_) / (256 * 8)), 256, 0, stream>>>(qw, sc, wb);

  const int nwg = (N_ / BN) * (M_ / BM);  // 16 * 32 = 512
  gemm_kernel<<<nwg, 512, 0, stream>>>(xb, wb, bias, out);
}